// Round 1
// baseline (1001.591 us; speedup 1.0000x reference)
//
#include <hip/hip_runtime.h>
#include <hip/hip_bf16.h>

#define B 4
#define H 480
#define W 640
#define HW (H*W)
#define BHW (B*H*W)
#define NKP 1024
#define RAD 4
#define THRESH 0.005f
#define CAP 32768          // candidate capacity per batch
#define NCHUNK 4           // CAP / 8192
#define CHUNK 8192
#define NCOL (B*NKP)       // 4096 columns in X
#define KTOT 704

// ---------------- NMS helpers ----------------

__global__ void zero_cnt(int* cnt) {
    if (threadIdx.x < 16) cnt[threadIdx.x] = 0;
}

__global__ void pool_h(const float* __restrict__ in, float* __restrict__ out) {
    int i = blockIdx.x * blockDim.x + threadIdx.x;
    if (i >= BHW) return;
    int x = i % W;
    int base = i - x;
    float m = -INFINITY;
    #pragma unroll
    for (int dx = -RAD; dx <= RAD; ++dx) {
        int xx = x + dx;
        if (xx >= 0 && xx < W) m = fmaxf(m, in[base + xx]);
    }
    out[i] = m;
}

__global__ void pool_v(const float* __restrict__ in, float* __restrict__ out) {
    int i = blockIdx.x * blockDim.x + threadIdx.x;
    if (i >= BHW) return;
    int r = i % HW;
    int y = r / W;
    float m = -INFINITY;
    #pragma unroll
    for (int dy = -RAD; dy <= RAD; ++dy) {
        int yy = y + dy;
        if (yy >= 0 && yy < H) m = fmaxf(m, in[i + (yy - y) * W]);
    }
    out[i] = m;
}

__global__ void mask_eq(const float* __restrict__ s, const float* __restrict__ p,
                        float* __restrict__ mask) {
    int i = blockIdx.x * blockDim.x + threadIdx.x;
    if (i >= BHW) return;
    mask[i] = (s[i] == p[i]) ? 1.0f : 0.0f;
}

// supp = pooled_mask > 0 ; SS = supp ? 0 : scores ; SUPP = supp ? 1 : 0
__global__ void supp_ss(const float* __restrict__ p, const float* __restrict__ s,
                        float* __restrict__ ss, float* __restrict__ supp) {
    int i = blockIdx.x * blockDim.x + threadIdx.x;
    if (i >= BHW) return;
    bool sp = p[i] > 0.0f;
    supp[i] = sp ? 1.0f : 0.0f;
    ss[i] = sp ? 0.0f : s[i];
}

// mask |= (ss == pooled_ss) & !supp
__global__ void update_mask(float* __restrict__ mask, const float* __restrict__ ss,
                            const float* __restrict__ p, const float* __restrict__ supp) {
    int i = blockIdx.x * blockDim.x + threadIdx.x;
    if (i >= BHW) return;
    bool nm = (ss[i] == p[i]) && (supp[i] == 0.0f);
    mask[i] = (mask[i] != 0.0f || nm) ? 1.0f : 0.0f;
}

// ---------------- candidate compaction ----------------

__global__ void compact(const float* __restrict__ s, const float* __restrict__ mask,
                        unsigned long long* __restrict__ cand, int* __restrict__ cnt) {
    int i = blockIdx.x * blockDim.x + threadIdx.x;
    if (i >= BHW) return;
    int b = i / HW;
    int r = i - b * HW;
    int y = r / W;
    int x = r - y * W;
    float sc = s[i];
    if (mask[i] != 0.0f && y >= 4 && y < H - 4 && x >= 4 && x < W - 4 && sc > THRESH) {
        int pos = atomicAdd(&cnt[b], 1);
        if (pos < CAP) {
            unsigned bits = __float_as_uint(sc) | 0x80000000u;  // positive float -> ordered
            unsigned long long key =
                ((unsigned long long)bits << 32) | (unsigned long long)(0xFFFFFFFFu - (unsigned)r);
            cand[(size_t)b * CAP + pos] = key;
        }
    }
}

// ---------------- bitonic sorts ----------------

__device__ __forceinline__ void bitonic_desc(unsigned long long* sk, int ns, int nt) {
    for (int k = 2; k <= ns; k <<= 1) {
        for (int j = k >> 1; j > 0; j >>= 1) {
            __syncthreads();
            for (int t = threadIdx.x; t < ns; t += nt) {
                int ixj = t ^ j;
                if (ixj > t) {
                    unsigned long long a = sk[t], bb = sk[ixj];
                    bool up = ((t & k) == 0);
                    // descending sort: in "up" region larger element goes first
                    if (up ? (a < bb) : (a > bb)) { sk[t] = bb; sk[ixj] = a; }
                }
            }
        }
    }
    __syncthreads();
}

// one block per (batch, chunk): sort 8192 candidates desc, emit top 1024
__global__ __launch_bounds__(1024) void sort_chunk(const unsigned long long* __restrict__ cand,
                                                   const int* __restrict__ cnt,
                                                   unsigned long long* __restrict__ ctops) {
    __shared__ unsigned long long sk[CHUNK];
    int b = blockIdx.x / NCHUNK;
    int c = blockIdx.x % NCHUNK;
    int m = cnt[b]; if (m > CAP) m = CAP;
    for (int t = threadIdx.x; t < CHUNK; t += 1024) {
        int g = c * CHUNK + t;
        sk[t] = (g < m) ? cand[(size_t)b * CAP + g] : 0ULL;
    }
    bitonic_desc(sk, CHUNK, 1024);
    int t = threadIdx.x;           // 1024 threads -> top 1024
    ctops[((size_t)b * NCHUNK + c) * NKP + t] = sk[t];
}

// one block per batch: merge 4*1024 chunk tops, emit kp/scores/final idx
__global__ __launch_bounds__(1024) void sort_final(const unsigned long long* __restrict__ ctops,
                                                   float* __restrict__ out,
                                                   int* __restrict__ fidx) {
    __shared__ unsigned long long sk[NCHUNK * NKP];
    int b = blockIdx.x;
    for (int t = threadIdx.x; t < NCHUNK * NKP; t += 1024)
        sk[t] = ctops[(size_t)b * NCHUNK * NKP + t];
    bitonic_desc(sk, NCHUNK * NKP, 1024);
    int n = threadIdx.x;
    unsigned long long key = sk[n];
    float kx, ky, sc;
    unsigned idx;
    if (key != 0ULL) {
        unsigned ord = (unsigned)(key >> 32);
        sc = __uint_as_float(ord ^ 0x80000000u);
        idx = 0xFFFFFFFFu - (unsigned)(key & 0xFFFFFFFFu);
        kx = (float)(idx % W);
        ky = (float)(idx / W);
    } else {
        sc = -1.0f; idx = 0; kx = 0.0f; ky = 0.0f;
    }
    int bn = b * NKP + n;
    out[bn * 2 + 0] = kx;
    out[bn * 2 + 1] = ky;
    out[B * NKP * 2 + bn] = sc;
    fidx[bn] = (int)idx;
}

// ---------------- descriptor sampling ----------------

template <int C>
__global__ void sample_kernel(const float* __restrict__ map, const int* __restrict__ fidx,
                              float* __restrict__ X, int h, int w, int s, int row0) {
    int bn = blockIdx.x;               // b*1024 + n
    int b = bn >> 10;
    int c = threadIdx.x;
    int idx = fidx[bn];
    float kx = (float)(idx % W);
    float ky = (float)(idx / W);
    // mimic reference op order
    float kxs = (kx - (float)s * 0.5f) + 0.5f;
    float kys = (ky - (float)s * 0.5f) + 0.5f;
    float gx = kxs / (float)(w * s - 1) * 2.0f - 1.0f;
    float gy = kys / (float)(h * s - 1) * 2.0f - 1.0f;
    float x = (gx + 1.0f) * 0.5f * (float)(w - 1);
    float y = (gy + 1.0f) * 0.5f * (float)(h - 1);
    float x0f = floorf(x), y0f = floorf(y);
    int x0 = (int)x0f, y0 = (int)y0f;
    float wx1 = x - x0f, wy1 = y - y0f;
    float wx0 = 1.0f - wx1, wy0 = 1.0f - wy1;
    const float* plane = map + ((size_t)(b * C + c)) * h * w;
    auto tap = [&](int xi, int yi) -> float {
        bool v = (xi >= 0) && (xi < w) && (yi >= 0) && (yi < h);
        int xc = min(max(xi, 0), w - 1);
        int yc = min(max(yi, 0), h - 1);
        return v ? plane[yc * w + xc] : 0.0f;
    };
    float v = tap(x0, y0) * (wx0 * wy0) + tap(x0 + 1, y0) * (wx1 * wy0) +
              tap(x0, y0 + 1) * (wx0 * wy1) + tap(x0 + 1, y0 + 1) * (wx1 * wy1);
    __shared__ float red[C];
    red[c] = v * v;
    __syncthreads();
    for (int off = C / 2; off > 0; off >>= 1) {
        if (c < off) red[c] += red[c + off];
        __syncthreads();
    }
    float norm = sqrtf(red[0]);
    float denom = fmaxf(norm, 1e-12f);
    X[(size_t)(row0 + c) * NCOL + bn] = v / denom;
}

// ---------------- fused weights ----------------

__global__ void fuse_weights(const float* __restrict__ merge_w, const float* __restrict__ lin0_w,
                             const float* __restrict__ lin1_w, const float* __restrict__ lin2_w,
                             float* __restrict__ Mw) {
    int e = blockIdx.x * blockDim.x + threadIdx.x;
    if (e >= 256 * KTOT) return;
    int o = e / KTOT;
    int j = e - o * KTOT;
    float acc = 0.0f;
    if (j < 64) {
        for (int k = 0; k < 64; ++k) acc += merge_w[o * KTOT + k] * lin2_w[k * 64 + j];
    } else if (j < 192) {
        int jj = j - 64;
        for (int k = 0; k < 128; ++k) acc += merge_w[o * KTOT + 64 + k] * lin1_w[k * 128 + jj];
    } else if (j < 448) {
        acc = merge_w[o * KTOT + j];
    } else {
        int jj = j - 448;
        for (int k = 0; k < 256; ++k) acc += merge_w[o * KTOT + 448 + k] * lin0_w[k * 256 + jj];
    }
    Mw[o * KTOT + j] = acc;
}

__global__ void fuse_bias(const float* __restrict__ merge_w, const float* __restrict__ merge_b,
                          const float* __restrict__ lin0_b, const float* __restrict__ lin1_b,
                          const float* __restrict__ lin2_b, float* __restrict__ biasf) {
    int o = threadIdx.x;
    float acc = merge_b[o];
    for (int k = 0; k < 64; ++k) acc += merge_w[o * KTOT + k] * lin2_b[k];
    for (int k = 0; k < 128; ++k) acc += merge_w[o * KTOT + 64 + k] * lin1_b[k];
    for (int k = 0; k < 256; ++k) acc += merge_w[o * KTOT + 448 + k] * lin0_b[k];
    biasf[o] = acc;
}

// ---------------- GEMM: out[256,4096] = Mw[256,704] * X[704,4096] + bias ----------------

__global__ __launch_bounds__(256) void gemm_desc(const float* __restrict__ Mw,
                                                 const float* __restrict__ X,
                                                 const float* __restrict__ biasf,
                                                 float* __restrict__ out) {
    __shared__ __align__(16) float As[64 * 16];   // [m][k]
    __shared__ __align__(16) float Bs[16 * 64];   // [k][n]
    int tid = threadIdx.x;
    int tx = tid & 15, ty = tid >> 4;
    int rowBase = blockIdx.y * 64;
    int colBase = blockIdx.x * 64;
    float acc[4][4] = {};
    for (int kt = 0; kt < KTOT / 16; ++kt) {
        int k0 = kt * 16;
        {
            int m = tid >> 2;
            int kq = (tid & 3) << 2;
            float4 va = *(const float4*)(Mw + (size_t)(rowBase + m) * KTOT + k0 + kq);
            *(float4*)&As[m * 16 + kq] = va;
            int kk = tid >> 4;
            int nq = (tid & 15) << 2;
            float4 vb = *(const float4*)(X + (size_t)(k0 + kk) * NCOL + colBase + nq);
            *(float4*)&Bs[kk * 64 + nq] = vb;
        }
        __syncthreads();
        #pragma unroll
        for (int kk = 0; kk < 16; ++kk) {
            float a[4], bv[4];
            #pragma unroll
            for (int i = 0; i < 4; ++i) a[i] = As[(ty * 4 + i) * 16 + kk];
            #pragma unroll
            for (int j = 0; j < 4; ++j) bv[j] = Bs[kk * 64 + tx * 4 + j];
            #pragma unroll
            for (int i = 0; i < 4; ++i)
                #pragma unroll
                for (int j = 0; j < 4; ++j) acc[i][j] += a[i] * bv[j];
        }
        __syncthreads();
    }
    #pragma unroll
    for (int i = 0; i < 4; ++i) {
        int o = rowBase + ty * 4 + i;
        float bia = biasf[o];
        #pragma unroll
        for (int j = 0; j < 4; ++j) {
            int col = colBase + tx * 4 + j;
            out[(size_t)(col >> 10) * (256 * NKP) + (size_t)o * NKP + (col & 1023)] =
                acc[i][j] + bia;
        }
    }
}

// ---------------- launch ----------------

extern "C" void kernel_launch(void* const* d_in, const int* in_sizes, int n_in,
                              void* d_out, int out_size, void* d_ws, size_t ws_size,
                              hipStream_t stream) {
    const float* scores  = (const float*)d_in[0];
    const float* d1      = (const float*)d_in[1];
    const float* d2      = (const float*)d_in[2];
    const float* cDa     = (const float*)d_in[3];
    const float* d4      = (const float*)d_in[4];
    const float* lin0_w  = (const float*)d_in[5];
    const float* lin0_b  = (const float*)d_in[6];
    const float* lin1_w  = (const float*)d_in[7];
    const float* lin1_b  = (const float*)d_in[8];
    const float* lin2_w  = (const float*)d_in[9];
    const float* lin2_b  = (const float*)d_in[10];
    const float* merge_w = (const float*)d_in[11];
    const float* merge_b = (const float*)d_in[12];
    float* out = (float*)d_out;

    char* ws = (char*)d_ws;
    float* T    = (float*)ws;
    float* P    = T + BHW;
    float* MASK = P + BHW;
    float* SS   = MASK + BHW;
    float* SUPP = SS + BHW;
    float* Xbuf = (float*)ws;  // aliases NMS buffers; used only after compaction
    unsigned long long* cand  = (unsigned long long*)(ws + 24576000);
    int* cnt                  = (int*)(ws + 25624576);
    unsigned long long* ctops = (unsigned long long*)(ws + 25624640);
    int* fidx                 = (int*)(ws + 25755712);
    float* Mw                 = (float*)(ws + 25772096);
    float* biasf              = (float*)(ws + 26492992);

    const int TB = 256;
    const int GB = BHW / TB;  // 4800

    zero_cnt<<<1, 64, 0, stream>>>(cnt);

    // simple_nms
    pool_h<<<GB, TB, 0, stream>>>(scores, T);
    pool_v<<<GB, TB, 0, stream>>>(T, P);
    mask_eq<<<GB, TB, 0, stream>>>(scores, P, MASK);
    for (int it = 0; it < 2; ++it) {
        pool_h<<<GB, TB, 0, stream>>>(MASK, T);
        pool_v<<<GB, TB, 0, stream>>>(T, P);
        supp_ss<<<GB, TB, 0, stream>>>(P, scores, SS, SUPP);
        pool_h<<<GB, TB, 0, stream>>>(SS, T);
        pool_v<<<GB, TB, 0, stream>>>(T, P);
        update_mask<<<GB, TB, 0, stream>>>(MASK, SS, P, SUPP);
    }

    // top-k
    compact<<<GB, TB, 0, stream>>>(scores, MASK, cand, cnt);
    sort_chunk<<<B * NCHUNK, 1024, 0, stream>>>(cand, cnt, ctops);
    sort_final<<<B, 1024, 0, stream>>>(ctops, out, fidx);

    // descriptor sampling into X[704][4096]
    sample_kernel<64><<<B * NKP, 64, 0, stream>>>(d1, fidx, Xbuf, 240, 320, 2, 0);
    sample_kernel<128><<<B * NKP, 128, 0, stream>>>(d2, fidx, Xbuf, 120, 160, 4, 64);
    sample_kernel<256><<<B * NKP, 256, 0, stream>>>(cDa, fidx, Xbuf, 60, 80, 8, 192);
    sample_kernel<256><<<B * NKP, 256, 0, stream>>>(d4, fidx, Xbuf, 30, 40, 16, 448);

    // fused weights + bias, then one GEMM
    fuse_weights<<<(256 * KTOT) / TB, TB, 0, stream>>>(merge_w, lin0_w, lin1_w, lin2_w, Mw);
    fuse_bias<<<1, 256, 0, stream>>>(merge_w, merge_b, lin0_b, lin1_b, lin2_b, biasf);
    gemm_desc<<<dim3(NCOL / 64, 256 / 64), 256, 0, stream>>>(Mw, Xbuf, biasf, out + B * NKP * 3);
}

// Round 2
// 489.398 us; speedup vs baseline: 2.0466x; 2.0466x over previous
//
#include <hip/hip_runtime.h>
#include <hip/hip_bf16.h>

#define B 4
#define H 480
#define W 640
#define HW (H*W)
#define BHW (B*H*W)
#define NKP 1024
#define THRESH 0.005f
#define CAP 16384          // candidate capacity per batch (~4x expected survivors)
#define NCHUNK 4
#define CHUNK 4096
#define NCOL (B*NKP)       // 4096 columns in X
#define KTOT 704

// ================= fused weights + bias + counter zero =================
// descriptors = merge_w . [lin2.X1 | lin1.X2 | X3 | lin0.X4] + bias
//             = Mw . X + biasf  with Mw = merge_w . blockdiag(lin2,lin1,I,lin0)
__global__ void fuse_all(const float* __restrict__ merge_w, const float* __restrict__ merge_b,
                         const float* __restrict__ lin0_w, const float* __restrict__ lin0_b,
                         const float* __restrict__ lin1_w, const float* __restrict__ lin1_b,
                         const float* __restrict__ lin2_w, const float* __restrict__ lin2_b,
                         float* __restrict__ Mw, float* __restrict__ biasf, int* __restrict__ cnt) {
    if (blockIdx.x == 704) {
        int o = threadIdx.x;
        if (o < 4) cnt[o * 64] = 0;   // padded counters, 256B apart
        float acc = merge_b[o];
        for (int k = 0; k < 64; ++k)  acc += merge_w[o * KTOT + k] * lin2_b[k];
        for (int k = 0; k < 128; ++k) acc += merge_w[o * KTOT + 64 + k] * lin1_b[k];
        for (int k = 0; k < 256; ++k) acc += merge_w[o * KTOT + 448 + k] * lin0_b[k];
        biasf[o] = acc;
        return;
    }
    int e = blockIdx.x * 256 + threadIdx.x;     // e < 256*704
    int o = e / KTOT;
    int j = e - o * KTOT;
    float acc = 0.0f;
    if (j < 64) {
        for (int k = 0; k < 64; ++k) acc += merge_w[o * KTOT + k] * lin2_w[k * 64 + j];
    } else if (j < 192) {
        int jj = j - 64;
        for (int k = 0; k < 128; ++k) acc += merge_w[o * KTOT + 64 + k] * lin1_w[k * 128 + jj];
    } else if (j < 448) {
        acc = merge_w[o * KTOT + j];
    } else {
        int jj = j - 448;
        for (int k = 0; k < 256; ++k) acc += merge_w[o * KTOT + 448 + k] * lin0_w[k * 256 + jj];
    }
    Mw[o * KTOT + j] = acc;
}

// ================= tiled 9x9 max-pool NMS (fused separable, LDS) =================
// grid (20,15,4), block 256; 32x32 output tile, 40x40 halo input

__global__ __launch_bounds__(256) void nms_a(const float* __restrict__ scores,
                                             float* __restrict__ mask) {
    __shared__ float tile[40][40];
    __shared__ float hm[40][32];
    int bz = blockIdx.z;
    int x0 = blockIdx.x * 32, y0 = blockIdx.y * 32;
    const float* sp = scores + bz * HW;
    for (int t = threadIdx.x; t < 1600; t += 256) {
        int ly = t / 40, lx = t - ly * 40;
        int gy = y0 - 4 + ly, gx = x0 - 4 + lx;
        tile[ly][lx] = (gy >= 0 && gy < H && gx >= 0 && gx < W) ? sp[gy * W + gx] : -INFINITY;
    }
    __syncthreads();
    for (int t = threadIdx.x; t < 1280; t += 256) {
        int ly = t >> 5, lx = t & 31;
        float m = tile[ly][lx];
        #pragma unroll
        for (int d = 1; d < 9; ++d) m = fmaxf(m, tile[ly][lx + d]);
        hm[ly][lx] = m;
    }
    __syncthreads();
    for (int t = threadIdx.x; t < 1024; t += 256) {
        int ly = t >> 5, lx = t & 31;
        float m = hm[ly][lx];
        #pragma unroll
        for (int d = 1; d < 9; ++d) m = fmaxf(m, hm[ly + d][lx]);
        float s = tile[ly + 4][lx + 4];
        mask[bz * HW + (y0 + ly) * W + x0 + lx] = (s == m) ? 1.0f : 0.0f;
    }
}

// pooled(mask) -> supp; ss = supp ? 0 : scores
__global__ __launch_bounds__(256) void nms_b(const float* __restrict__ mask_in,
                                             const float* __restrict__ scores,
                                             float* __restrict__ ss, float* __restrict__ supp) {
    __shared__ float tile[40][40];
    __shared__ float hm[40][32];
    int bz = blockIdx.z;
    int x0 = blockIdx.x * 32, y0 = blockIdx.y * 32;
    const float* mp = mask_in + bz * HW;
    for (int t = threadIdx.x; t < 1600; t += 256) {
        int ly = t / 40, lx = t - ly * 40;
        int gy = y0 - 4 + ly, gx = x0 - 4 + lx;
        tile[ly][lx] = (gy >= 0 && gy < H && gx >= 0 && gx < W) ? mp[gy * W + gx] : -INFINITY;
    }
    __syncthreads();
    for (int t = threadIdx.x; t < 1280; t += 256) {
        int ly = t >> 5, lx = t & 31;
        float m = tile[ly][lx];
        #pragma unroll
        for (int d = 1; d < 9; ++d) m = fmaxf(m, tile[ly][lx + d]);
        hm[ly][lx] = m;
    }
    __syncthreads();
    for (int t = threadIdx.x; t < 1024; t += 256) {
        int ly = t >> 5, lx = t & 31;
        float m = hm[ly][lx];
        #pragma unroll
        for (int d = 1; d < 9; ++d) m = fmaxf(m, hm[ly + d][lx]);
        int g = bz * HW + (y0 + ly) * W + x0 + lx;
        bool sp = m > 0.0f;
        supp[g] = sp ? 1.0f : 0.0f;
        ss[g] = sp ? 0.0f : scores[g];
    }
}

// mask |= (ss == pooled(ss)) & !supp
__global__ __launch_bounds__(256) void nms_c(const float* __restrict__ ss_in,
                                             const float* __restrict__ supp,
                                             float* __restrict__ mask) {
    __shared__ float tile[40][40];
    __shared__ float hm[40][32];
    int bz = blockIdx.z;
    int x0 = blockIdx.x * 32, y0 = blockIdx.y * 32;
    const float* sp = ss_in + bz * HW;
    for (int t = threadIdx.x; t < 1600; t += 256) {
        int ly = t / 40, lx = t - ly * 40;
        int gy = y0 - 4 + ly, gx = x0 - 4 + lx;
        tile[ly][lx] = (gy >= 0 && gy < H && gx >= 0 && gx < W) ? sp[gy * W + gx] : -INFINITY;
    }
    __syncthreads();
    for (int t = threadIdx.x; t < 1280; t += 256) {
        int ly = t >> 5, lx = t & 31;
        float m = tile[ly][lx];
        #pragma unroll
        for (int d = 1; d < 9; ++d) m = fmaxf(m, tile[ly][lx + d]);
        hm[ly][lx] = m;
    }
    __syncthreads();
    for (int t = threadIdx.x; t < 1024; t += 256) {
        int ly = t >> 5, lx = t & 31;
        float m = hm[ly][lx];
        #pragma unroll
        for (int d = 1; d < 9; ++d) m = fmaxf(m, hm[ly + d][lx]);
        int g = bz * HW + (y0 + ly) * W + x0 + lx;
        bool nm = (tile[ly + 4][lx + 4] == m) && (supp[g] == 0.0f);
        float old = mask[g];
        mask[g] = (old != 0.0f || nm) ? 1.0f : 0.0f;
    }
}

// ================= candidate compaction (block-aggregated atomics) =================
// 8 px/thread, 2048 px/block, 600 blocks; one global atomic per block on padded counters
__global__ __launch_bounds__(256) void compact(const float* __restrict__ s,
                                               const float* __restrict__ mask,
                                               unsigned long long* __restrict__ cand,
                                               int* __restrict__ cnt) {
    __shared__ int lcnt, gbase;
    if (threadIdx.x == 0) lcnt = 0;
    __syncthreads();
    int b = blockIdx.x / 150;
    int base = blockIdx.x * 2048 + threadIdx.x * 8;
    int r0 = base - b * HW;
    float sv[8], mv[8];
    *(float4*)&sv[0] = *(const float4*)(s + base);
    *(float4*)&sv[4] = *(const float4*)(s + base + 4);
    *(float4*)&mv[0] = *(const float4*)(mask + base);
    *(float4*)&mv[4] = *(const float4*)(mask + base + 4);
    unsigned long long keys[8];
    int nl = 0;
    #pragma unroll
    for (int q = 0; q < 8; ++q) {
        int r = r0 + q;
        int y = r / W;
        int x = r - y * W;
        if (mv[q] != 0.0f && y >= 4 && y < H - 4 && x >= 4 && x < W - 4 && sv[q] > THRESH) {
            unsigned bits = __float_as_uint(sv[q]) | 0x80000000u;
            keys[nl++] = ((unsigned long long)bits << 32) |
                         (unsigned long long)(0xFFFFFFFFu - (unsigned)r);
        }
    }
    int lpos = 0;
    if (nl) lpos = atomicAdd(&lcnt, nl);
    __syncthreads();
    if (threadIdx.x == 0) gbase = (lcnt > 0) ? atomicAdd(&cnt[b * 64], lcnt) : 0;
    __syncthreads();
    for (int j = 0; j < nl; ++j) {
        int p = gbase + lpos + j;
        if (p < CAP) cand[(size_t)b * CAP + p] = keys[j];
    }
}

// ================= bitonic sorts =================

__device__ __forceinline__ void bitonic_desc(unsigned long long* sk, int ns, int nt) {
    for (int k = 2; k <= ns; k <<= 1) {
        for (int j = k >> 1; j > 0; j >>= 1) {
            __syncthreads();
            for (int t = threadIdx.x; t < ns; t += nt) {
                int ixj = t ^ j;
                if (ixj > t) {
                    unsigned long long a = sk[t], bb = sk[ixj];
                    bool up = ((t & k) == 0);
                    if (up ? (a < bb) : (a > bb)) { sk[t] = bb; sk[ixj] = a; }
                }
            }
        }
    }
    __syncthreads();
}

__global__ __launch_bounds__(1024) void sort_chunk(const unsigned long long* __restrict__ cand,
                                                   const int* __restrict__ cnt,
                                                   unsigned long long* __restrict__ ctops) {
    __shared__ unsigned long long sk[CHUNK];
    int b = blockIdx.x >> 2;
    int c = blockIdx.x & 3;
    int m = cnt[b * 64]; if (m > CAP) m = CAP;
    for (int t = threadIdx.x; t < CHUNK; t += 1024) {
        int g = c * CHUNK + t;
        sk[t] = (g < m) ? cand[(size_t)b * CAP + g] : 0ULL;
    }
    bitonic_desc(sk, CHUNK, 1024);
    ctops[((size_t)b * NCHUNK + c) * NKP + threadIdx.x] = sk[threadIdx.x];
}

__global__ __launch_bounds__(1024) void sort_final(const unsigned long long* __restrict__ ctops,
                                                   float* __restrict__ out,
                                                   int* __restrict__ fidx) {
    __shared__ unsigned long long sk[NCHUNK * NKP];
    int b = blockIdx.x;
    for (int t = threadIdx.x; t < NCHUNK * NKP; t += 1024)
        sk[t] = ctops[(size_t)b * NCHUNK * NKP + t];
    bitonic_desc(sk, NCHUNK * NKP, 1024);
    int n = threadIdx.x;
    unsigned long long key = sk[n];
    float kx, ky, sc;
    unsigned idx;
    if (key != 0ULL) {
        unsigned ord = (unsigned)(key >> 32);
        sc = __uint_as_float(ord ^ 0x80000000u);
        idx = 0xFFFFFFFFu - (unsigned)(key & 0xFFFFFFFFu);
        kx = (float)(idx % W);
        ky = (float)(idx / W);
    } else {
        sc = -1.0f; idx = 0; kx = 0.0f; ky = 0.0f;
    }
    int bn = b * NKP + n;
    out[bn * 2 + 0] = kx;
    out[bn * 2 + 1] = ky;
    out[B * NKP * 2 + bn] = sc;
    fidx[bn] = (int)idx;
}

// ================= fused descriptor sampling (all 4 pyramids, one block/kp) =================
// X is column-major: X[bn*KTOT + row] -> sampler writes coalesced

__global__ __launch_bounds__(704) void sample_all(const float* __restrict__ d1,
                                                  const float* __restrict__ d2,
                                                  const float* __restrict__ cDa,
                                                  const float* __restrict__ d4,
                                                  const int* __restrict__ fidx,
                                                  float* __restrict__ X) {
    __shared__ float red[KTOT];
    int bn = blockIdx.x;
    int b = bn >> 10;
    int c = threadIdx.x;
    int idx = fidx[bn];
    float kx = (float)(idx % W);
    float ky = (float)(idx / W);

    const float* map; int h, w, s, base, segsize, cl, C;
    if (c < 64)       { map = d1;  h = 240; w = 320; s = 2;  base = 0;   segsize = 64;  cl = c;       C = 64; }
    else if (c < 192) { map = d2;  h = 120; w = 160; s = 4;  base = 64;  segsize = 128; cl = c - 64;  C = 128; }
    else if (c < 448) { map = cDa; h = 60;  w = 80;  s = 8;  base = 192; segsize = 256; cl = c - 192; C = 256; }
    else              { map = d4;  h = 30;  w = 40;  s = 16; base = 448; segsize = 256; cl = c - 448; C = 256; }

    // mimic reference op order
    float kxs = (kx - (float)s * 0.5f) + 0.5f;
    float kys = (ky - (float)s * 0.5f) + 0.5f;
    float gx = kxs / (float)(w * s - 1) * 2.0f - 1.0f;
    float gy = kys / (float)(h * s - 1) * 2.0f - 1.0f;
    float x = (gx + 1.0f) * 0.5f * (float)(w - 1);
    float y = (gy + 1.0f) * 0.5f * (float)(h - 1);
    float x0f = floorf(x), y0f = floorf(y);
    int x0 = (int)x0f, y0 = (int)y0f;
    float wx1 = x - x0f, wy1 = y - y0f;
    float wx0 = 1.0f - wx1, wy0 = 1.0f - wy1;
    const float* plane = map + ((size_t)(b * C + cl)) * h * w;
    auto tap = [&](int xi, int yi) -> float {
        bool v = (xi >= 0) && (xi < w) && (yi >= 0) && (yi < h);
        int xc = min(max(xi, 0), w - 1);
        int yc = min(max(yi, 0), h - 1);
        return v ? plane[yc * w + xc] : 0.0f;
    };
    float v = tap(x0, y0) * (wx0 * wy0) + tap(x0 + 1, y0) * (wx1 * wy0) +
              tap(x0, y0 + 1) * (wx0 * wy1) + tap(x0 + 1, y0 + 1) * (wx1 * wy1);

    red[c] = v * v;
    __syncthreads();
    #pragma unroll
    for (int off = 128; off > 0; off >>= 1) {
        if (off < segsize && cl < off) red[c] += red[c + off];
        __syncthreads();
    }
    float norm = sqrtf(red[base]);
    float denom = fmaxf(norm, 1e-12f);
    X[(size_t)bn * KTOT + c] = v / denom;
}

// ================= GEMM: out[256,4096] = Mw[256,704] * X^T + bias =================
// X column-major [4096][704]; B-tile transposed in LDS

__global__ __launch_bounds__(256) void gemm_desc(const float* __restrict__ Mw,
                                                 const float* __restrict__ X,
                                                 const float* __restrict__ biasf,
                                                 float* __restrict__ out) {
    __shared__ float As[64 * 20];   // [m][k], stride 20 (16B-aligned rows, bank-safe)
    __shared__ float Bs[16 * 65];   // [k][n], stride 65
    int tid = threadIdx.x;
    int tx = tid & 15, ty = tid >> 4;
    int rowBase = blockIdx.y * 64;
    int colBase = blockIdx.x * 64;
    float acc[4][4] = {};
    for (int kt = 0; kt < KTOT / 16; ++kt) {
        int k0 = kt * 16;
        {
            int m = tid >> 2;
            int kq = (tid & 3) << 2;
            float4 va = *(const float4*)(Mw + (size_t)(rowBase + m) * KTOT + k0 + kq);
            *(float4*)&As[m * 20 + kq] = va;
            int col = tid >> 2;
            float4 vb = *(const float4*)(X + (size_t)(colBase + col) * KTOT + k0 + kq);
            Bs[(kq + 0) * 65 + col] = vb.x;
            Bs[(kq + 1) * 65 + col] = vb.y;
            Bs[(kq + 2) * 65 + col] = vb.z;
            Bs[(kq + 3) * 65 + col] = vb.w;
        }
        __syncthreads();
        #pragma unroll
        for (int kk = 0; kk < 16; ++kk) {
            float a[4], bv[4];
            #pragma unroll
            for (int i = 0; i < 4; ++i) a[i] = As[(ty * 4 + i) * 20 + kk];
            #pragma unroll
            for (int j = 0; j < 4; ++j) bv[j] = Bs[kk * 65 + tx * 4 + j];
            #pragma unroll
            for (int i = 0; i < 4; ++i)
                #pragma unroll
                for (int j = 0; j < 4; ++j) acc[i][j] += a[i] * bv[j];
        }
        __syncthreads();
    }
    #pragma unroll
    for (int i = 0; i < 4; ++i) {
        int o = rowBase + ty * 4 + i;
        float bia = biasf[o];
        #pragma unroll
        for (int j = 0; j < 4; ++j) {
            int col = colBase + tx * 4 + j;
            out[(size_t)(col >> 10) * (256 * NKP) + (size_t)o * NKP + (col & 1023)] =
                acc[i][j] + bia;
        }
    }
}

// ================= launch =================

extern "C" void kernel_launch(void* const* d_in, const int* in_sizes, int n_in,
                              void* d_out, int out_size, void* d_ws, size_t ws_size,
                              hipStream_t stream) {
    const float* scores  = (const float*)d_in[0];
    const float* d1      = (const float*)d_in[1];
    const float* d2      = (const float*)d_in[2];
    const float* cDa     = (const float*)d_in[3];
    const float* d4      = (const float*)d_in[4];
    const float* lin0_w  = (const float*)d_in[5];
    const float* lin0_b  = (const float*)d_in[6];
    const float* lin1_w  = (const float*)d_in[7];
    const float* lin1_b  = (const float*)d_in[8];
    const float* lin2_w  = (const float*)d_in[9];
    const float* lin2_b  = (const float*)d_in[10];
    const float* merge_w = (const float*)d_in[11];
    const float* merge_b = (const float*)d_in[12];
    float* out = (float*)d_out;

    char* ws = (char*)d_ws;
    float* MASK = (float*)ws;                 // BHW floats
    float* SS   = MASK + BHW;                 // BHW floats
    float* SUPP = SS + BHW;                   // BHW floats -> ends at 14,745,600 B
    float* Xbuf = (float*)ws;                 // aliases NMS buffers (used after sorts)
    unsigned long long* cand  = (unsigned long long*)(ws + 14745600);  // 524,288 B
    int* cnt                  = (int*)(ws + 15269888);                 // 1,024 B (padded)
    unsigned long long* ctops = (unsigned long long*)(ws + 15270912);  // 131,072 B
    int* fidx                 = (int*)(ws + 15401984);                 // 16,384 B
    float* Mw                 = (float*)(ws + 15418368);               // 720,896 B
    float* biasf              = (float*)(ws + 16139264);               // 1,024 B

    dim3 tgrid(W / 32, H / 32, B);   // (20,15,4)

    fuse_all<<<705, 256, 0, stream>>>(merge_w, merge_b, lin0_w, lin0_b, lin1_w, lin1_b,
                                      lin2_w, lin2_b, Mw, biasf, cnt);

    // simple_nms: 5 fused tiled kernels
    nms_a<<<tgrid, 256, 0, stream>>>(scores, MASK);
    nms_b<<<tgrid, 256, 0, stream>>>(MASK, scores, SS, SUPP);
    nms_c<<<tgrid, 256, 0, stream>>>(SS, SUPP, MASK);
    nms_b<<<tgrid, 256, 0, stream>>>(MASK, scores, SS, SUPP);
    nms_c<<<tgrid, 256, 0, stream>>>(SS, SUPP, MASK);

    // top-k
    compact<<<BHW / 2048, 256, 0, stream>>>(scores, MASK, cand, cnt);
    sort_chunk<<<B * NCHUNK, 1024, 0, stream>>>(cand, cnt, ctops);
    sort_final<<<B, 1024, 0, stream>>>(ctops, out, fidx);

    // fused descriptor sampling into X[4096][704] (column-major)
    sample_all<<<B * NKP, KTOT, 0, stream>>>(d1, d2, cDa, d4, fidx, Xbuf);

    // one GEMM
    gemm_desc<<<dim3(NCOL / 64, 256 / 64), 256, 0, stream>>>(Mw, Xbuf, biasf, out + B * NKP * 3);
}

// Round 4
// 401.312 us; speedup vs baseline: 2.4958x; 1.2195x over previous
//
#include <hip/hip_runtime.h>
#include <hip/hip_bf16.h>

#define B 4
#define H 480
#define W 640
#define HW (H*W)
#define BHW (B*H*W)
#define NKP 1024
#define THRESH 0.005f
#define CAP 16384
#define NCOL (B*NKP)
#define KTOT 704

typedef __attribute__((ext_vector_type(4))) short s4v;
typedef __attribute__((ext_vector_type(8))) short s8v;
typedef __attribute__((ext_vector_type(4))) float f4v;

__device__ __forceinline__ short f2bf(float f) {
    __hip_bfloat16 h = __float2bfloat16(f);
    return *(short*)&h;
}

// ================= fused weights + bias + counter zero =================
__global__ void fuse_all(const float* __restrict__ merge_w, const float* __restrict__ merge_b,
                         const float* __restrict__ lin0_w, const float* __restrict__ lin0_b,
                         const float* __restrict__ lin1_w, const float* __restrict__ lin1_b,
                         const float* __restrict__ lin2_w, const float* __restrict__ lin2_b,
                         float* __restrict__ Mw, float* __restrict__ biasf, int* __restrict__ cnt) {
    if (blockIdx.x == 704) {
        int o = threadIdx.x;
        if (o < 4) cnt[o * 64] = 0;
        float acc = merge_b[o];
        for (int k = 0; k < 64; ++k)  acc += merge_w[o * KTOT + k] * lin2_b[k];
        for (int k = 0; k < 128; ++k) acc += merge_w[o * KTOT + 64 + k] * lin1_b[k];
        for (int k = 0; k < 256; ++k) acc += merge_w[o * KTOT + 448 + k] * lin0_b[k];
        biasf[o] = acc;
        return;
    }
    int e = blockIdx.x * 256 + threadIdx.x;
    int o = e / KTOT;
    int j = e - o * KTOT;
    float acc = 0.0f;
    if (j < 64) {
        for (int k = 0; k < 64; ++k) acc += merge_w[o * KTOT + k] * lin2_w[k * 64 + j];
    } else if (j < 192) {
        int jj = j - 64;
        for (int k = 0; k < 128; ++k) acc += merge_w[o * KTOT + 64 + k] * lin1_w[k * 128 + jj];
    } else if (j < 448) {
        acc = merge_w[o * KTOT + j];
    } else {
        int jj = j - 448;
        for (int k = 0; k < 256; ++k) acc += merge_w[o * KTOT + 448 + k] * lin0_w[k * 256 + jj];
    }
    Mw[o * KTOT + j] = acc;
}

// ================= NMS stage 1: mask0 = (S == pool9(S)) =================
__global__ __launch_bounds__(256) void nms1(const float* __restrict__ scores,
                                            float* __restrict__ mask) {
    __shared__ float tile[40][40];
    __shared__ float hm[40][32];
    int bz = blockIdx.z;
    int x0 = blockIdx.x * 32, y0 = blockIdx.y * 32;
    const float* sp = scores + bz * HW;
    for (int t = threadIdx.x; t < 1600; t += 256) {
        int ly = t / 40, lx = t - ly * 40;
        int gy = y0 - 4 + ly, gx = x0 - 4 + lx;
        tile[ly][lx] = (gy >= 0 && gy < H && gx >= 0 && gx < W) ? sp[gy * W + gx] : -INFINITY;
    }
    __syncthreads();
    for (int t = threadIdx.x; t < 1280; t += 256) {
        int ly = t >> 5, lx = t & 31;
        float m = tile[ly][lx];
        #pragma unroll
        for (int d = 1; d < 9; ++d) m = fmaxf(m, tile[ly][lx + d]);
        hm[ly][lx] = m;
    }
    __syncthreads();
    for (int t = threadIdx.x; t < 1024; t += 256) {
        int ly = t >> 5, lx = t & 31;
        float m = hm[ly][lx];
        #pragma unroll
        for (int d = 1; d < 9; ++d) m = fmaxf(m, hm[ly + d][lx]);
        float s = tile[ly + 4][lx + 4];
        mask[bz * HW + (y0 + ly) * W + x0 + lx] = (s == m) ? 1.0f : 0.0f;
    }
}

// ===== NMS stage 2: remaining 4 pools (2 NMS iterations) fused in LDS + compaction =====
__global__ __launch_bounds__(256) void nms2_compact(const float* __restrict__ scores,
                                                    const float* __restrict__ mask0,
                                                    unsigned long long* __restrict__ cand,
                                                    int* __restrict__ cnt) {
    __shared__ float Sm[56 * 56];   // S on local [4,60)
    __shared__ float Mm[64 * 64];   // mask on local [0,64)
    __shared__ float Zm[56 * 56];   // Z on local [4,60)
    __shared__ float Tm[64 * 56];   // h-pass temp
    __shared__ int lcnt, gbase;
    int bz = blockIdx.z;
    int x0 = blockIdx.x * 32, y0 = blockIdx.y * 32;
    const float* sp = scores + bz * HW;
    const float* mp = mask0 + bz * HW;
    if (threadIdx.x == 0) lcnt = 0;
    for (int t = threadIdx.x; t < 4096; t += 256) {
        int ly = t >> 6, lx = t & 63;
        int gy = y0 - 16 + ly, gx = x0 - 16 + lx;
        Mm[t] = (gy >= 0 && gy < H && gx >= 0 && gx < W) ? mp[gy * W + gx] : 0.0f;
    }
    for (int t = threadIdx.x; t < 3136; t += 256) {
        int i = t / 56, j = t - i * 56;
        int gy = y0 - 12 + i, gx = x0 - 12 + j;
        Sm[t] = (gy >= 0 && gy < H && gx >= 0 && gx < W) ? sp[gy * W + gx] : -1.0f;
    }
    __syncthreads();
    for (int t = threadIdx.x; t < 3584; t += 256) {
        int i = t / 56, c = t - i * 56;
        float m = Mm[i * 64 + c];
        #pragma unroll
        for (int d = 1; d < 9; ++d) m = fmaxf(m, Mm[i * 64 + c + d]);
        Tm[i * 56 + c] = m;
    }
    __syncthreads();
    for (int t = threadIdx.x; t < 3136; t += 256) {
        int i = t / 56, c = t - i * 56;
        float m = Tm[i * 56 + c];
        #pragma unroll
        for (int d = 1; d < 9; ++d) m = fmaxf(m, Tm[(i + d) * 56 + c]);
        Zm[t] = (m > 0.0f) ? -1.0f : Sm[t];
    }
    __syncthreads();
    for (int t = threadIdx.x; t < 2688; t += 256) {
        int i = t / 48, c = t - i * 48;
        float m = Zm[i * 56 + c];
        #pragma unroll
        for (int d = 1; d < 9; ++d) m = fmaxf(m, Zm[i * 56 + c + d]);
        Tm[i * 56 + c] = m;
    }
    __syncthreads();
    for (int t = threadIdx.x; t < 2304; t += 256) {
        int r = t / 48, c = t - r * 48;
        float m = Tm[r * 56 + c];
        #pragma unroll
        for (int d = 1; d < 9; ++d) m = fmaxf(m, Tm[(r + d) * 56 + c]);
        float Zc = Zm[(r + 4) * 56 + c + 4];
        int mi = (r + 8) * 64 + c + 8;
        bool nm = (Zc == m) && (Zc >= 0.0f);
        Mm[mi] = (Mm[mi] != 0.0f || nm) ? 1.0f : 0.0f;
    }
    __syncthreads();
    for (int t = threadIdx.x; t < 1920; t += 256) {
        int r = t / 40, c = t - r * 40;
        float m = Mm[(r + 8) * 64 + c + 8];
        #pragma unroll
        for (int d = 1; d < 9; ++d) m = fmaxf(m, Mm[(r + 8) * 64 + c + 8 + d]);
        Tm[r * 56 + c] = m;
    }
    __syncthreads();
    for (int t = threadIdx.x; t < 1600; t += 256) {
        int r = t / 40, c = t - r * 40;
        float m = Tm[r * 56 + c];
        #pragma unroll
        for (int d = 1; d < 9; ++d) m = fmaxf(m, Tm[(r + d) * 56 + c]);
        int zi = (r + 8) * 56 + c + 8;
        Zm[zi] = (m > 0.0f) ? -1.0f : Sm[zi];
    }
    __syncthreads();
    for (int t = threadIdx.x; t < 1280; t += 256) {
        int r = t / 32, c = t & 31;
        float m = Zm[(r + 8) * 56 + c + 8];
        #pragma unroll
        for (int d = 1; d < 9; ++d) m = fmaxf(m, Zm[(r + 8) * 56 + c + 8 + d]);
        Tm[r * 56 + c] = m;
    }
    __syncthreads();
    unsigned long long keys[4];
    int nl = 0;
    #pragma unroll
    for (int q = 0; q < 4; ++q) {
        int t = threadIdx.x + q * 256;
        int r3 = t >> 5, c = t & 31;
        float m = Tm[r3 * 56 + c];
        #pragma unroll
        for (int d = 1; d < 9; ++d) m = fmaxf(m, Tm[(r3 + d) * 56 + c]);
        float Zc = Zm[(r3 + 12) * 56 + c + 12];
        bool fin = (Mm[(r3 + 16) * 64 + c + 16] != 0.0f) || ((Zc == m) && (Zc >= 0.0f));
        int gy = y0 + r3, gx = x0 + c;
        float sc = Sm[(r3 + 12) * 56 + c + 12];
        if (fin && gy >= 4 && gy < H - 4 && gx >= 4 && gx < W - 4 && sc > THRESH) {
            unsigned r = (unsigned)(gy * W + gx);
            unsigned bits = __float_as_uint(sc) | 0x80000000u;
            keys[nl++] = ((unsigned long long)bits << 32) |
                         (unsigned long long)(0xFFFFFFFFu - r);
        }
    }
    int lpos = 0;
    if (nl) lpos = atomicAdd(&lcnt, nl);
    __syncthreads();
    if (threadIdx.x == 0) gbase = (lcnt > 0) ? atomicAdd(&cnt[bz * 64], lcnt) : 0;
    __syncthreads();
    for (int j = 0; j < nl; ++j) {
        int p = gbase + lpos + j;
        if (p < CAP) cand[(size_t)bz * CAP + p] = keys[j];
    }
}

// ===== topk: TWO-LEVEL histogram select (22-bit prefix) + bitonic; emits spatial perm =====
__global__ __launch_bounds__(1024) void topk(const unsigned long long* __restrict__ cand,
                                             const int* __restrict__ cnt,
                                             float* __restrict__ out, int* __restrict__ fidx,
                                             int* __restrict__ perm) {
    __shared__ int hist[2048];
    __shared__ unsigned long long buf[4096];
    __shared__ int scnt, spiv1, spiv2, sabove;
    int b = blockIdx.x, tid = threadIdx.x;
    int m = cnt[b * 64]; if (m > CAP) m = CAP;
    const unsigned long long* cb = cand + (size_t)b * CAP;
    int target = (m < 1024) ? m : 1024;

    hist[tid] = 0; hist[tid + 1024] = 0;
    if (tid == 0) { scnt = 0; spiv1 = 2048; spiv2 = 0; sabove = 0; }
    __syncthreads();
    // pass 1: histogram of key bits [63:53]
    for (int i = tid; i < m; i += 1024)
        atomicAdd(&hist[(int)(cb[i] >> 53) & 0x7FF], 1);
    __syncthreads();
    for (int d = 1; d < 2048; d <<= 1) {
        int v0 = hist[tid] + ((tid + d < 2048) ? hist[tid + d] : 0);
        int v1 = hist[tid + 1024] + ((tid + 1024 + d < 2048) ? hist[tid + 1024 + d] : 0);
        __syncthreads();
        hist[tid] = v0; hist[tid + 1024] = v1;
        __syncthreads();
    }
    if (target > 0) {
        for (int t = tid; t < 2048; t += 1024) {
            int c = hist[t];
            int cn = (t < 2047) ? hist[t + 1] : 0;
            if (c >= target && cn < target) { spiv1 = t; sabove = cn; }
        }
    }
    __syncthreads();
    int piv1 = spiv1;
    int target2 = target - sabove;   // >= 1 when target > 0
    // pass 2: histogram of bits [52:42] within pivot bin
    hist[tid] = 0; hist[tid + 1024] = 0;
    __syncthreads();
    for (int i = tid; i < m; i += 1024) {
        unsigned long long k = cb[i];
        if (((int)(k >> 53) & 0x7FF) == piv1)
            atomicAdd(&hist[(int)(k >> 42) & 0x7FF], 1);
    }
    __syncthreads();
    for (int d = 1; d < 2048; d <<= 1) {
        int v0 = hist[tid] + ((tid + d < 2048) ? hist[tid + d] : 0);
        int v1 = hist[tid + 1024] + ((tid + 1024 + d < 2048) ? hist[tid + 1024 + d] : 0);
        __syncthreads();
        hist[tid] = v0; hist[tid + 1024] = v1;
        __syncthreads();
    }
    if (target > 0) {
        for (int t = tid; t < 2048; t += 1024) {
            int c = hist[t];
            int cn = (t < 2047) ? hist[t + 1] : 0;
            if (c >= target2 && cn < target2) spiv2 = t;
        }
    }
    __syncthreads();
    int piv2 = spiv2;
    // select: bin1 > piv1, or bin1 == piv1 && bin2 >= piv2  (~target + few keys)
    for (int i = tid; i < m; i += 1024) {
        unsigned long long k = cb[i];
        int b1 = (int)(k >> 53) & 0x7FF;
        bool sel = (target > 0) &&
                   (b1 > piv1 || (b1 == piv1 && (((int)(k >> 42) & 0x7FF) >= piv2)));
        if (sel) {
            int p = atomicAdd(&scnt, 1);
            if (p < 4096) buf[p] = k;
        }
    }
    __syncthreads();
    int sc_ = scnt; if (sc_ > 4096) sc_ = 4096;
    int ns = 1024; while (ns < sc_) ns <<= 1;
    for (int t = tid; t < ns; t += 1024) if (t >= sc_) buf[t] = 0ULL;
    __syncthreads();
    for (int k = 2; k <= ns; k <<= 1)
        for (int j = k >> 1; j > 0; j >>= 1) {
            __syncthreads();
            for (int t = tid; t < ns; t += 1024) {
                int ixj = t ^ j;
                if (ixj > t) {
                    unsigned long long a = buf[t], bb = buf[ixj];
                    if (((t & k) == 0) ? (a < bb) : (a > bb)) { buf[t] = bb; buf[ixj] = a; }
                }
            }
        }
    __syncthreads();
    unsigned long long key = buf[tid];
    float kx, ky, sc;
    unsigned idx;
    if (key != 0ULL) {
        unsigned ord = (unsigned)(key >> 32);
        sc = __uint_as_float(ord ^ 0x80000000u);
        idx = 0xFFFFFFFFu - (unsigned)(key & 0xFFFFFFFFu);
        kx = (float)(idx % W);
        ky = (float)(idx / W);
    } else {
        sc = -1.0f; idx = 0; kx = 0.0f; ky = 0.0f;
    }
    int bn = b * NKP + tid;
    out[bn * 2 + 0] = kx;
    out[bn * 2 + 1] = ky;
    out[B * NKP * 2 + bn] = sc;
    fidx[bn] = (int)idx;
    __syncthreads();
    // spatial sort: keys (pixel<<10)|n ascending -> processing perm
    unsigned* b32 = (unsigned*)buf;
    b32[tid] = (idx << 10) | (unsigned)tid;
    for (int k = 2; k <= 1024; k <<= 1)
        for (int j = k >> 1; j > 0; j >>= 1) {
            __syncthreads();
            int ixj = tid ^ j;
            if (ixj > tid) {
                unsigned a = b32[tid], bb = b32[ixj];
                if (((tid & k) == 0) ? (a > bb) : (a < bb)) { b32[tid] = bb; b32[ixj] = a; }
            }
        }
    __syncthreads();
    perm[b * NKP + tid] = (int)(b32[tid] & 1023u);
}

// ===== fused descriptor sampling; blocks walk keypoints in spatial order =====
__global__ __launch_bounds__(704) void sample_all(const float* __restrict__ d1,
                                                  const float* __restrict__ d2,
                                                  const float* __restrict__ cDa,
                                                  const float* __restrict__ d4,
                                                  const int* __restrict__ fidx,
                                                  const int* __restrict__ perm,
                                                  float* __restrict__ X) {
    __shared__ float red[KTOT];
    int bn2 = blockIdx.x;
    int b = bn2 >> 10;
    int col = (b << 10) | perm[bn2];
    int c = threadIdx.x;
    int idx = fidx[col];
    float kx = (float)(idx % W);
    float ky = (float)(idx / W);

    const float* map; int h, w, s, base, segsize, cl, C;
    if (c < 64)       { map = d1;  h = 240; w = 320; s = 2;  base = 0;   segsize = 64;  cl = c;       C = 64; }
    else if (c < 192) { map = d2;  h = 120; w = 160; s = 4;  base = 64;  segsize = 128; cl = c - 64;  C = 128; }
    else if (c < 448) { map = cDa; h = 60;  w = 80;  s = 8;  base = 192; segsize = 256; cl = c - 192; C = 256; }
    else              { map = d4;  h = 30;  w = 40;  s = 16; base = 448; segsize = 256; cl = c - 448; C = 256; }

    float kxs = (kx - (float)s * 0.5f) + 0.5f;
    float kys = (ky - (float)s * 0.5f) + 0.5f;
    float gx = kxs / (float)(w * s - 1) * 2.0f - 1.0f;
    float gy = kys / (float)(h * s - 1) * 2.0f - 1.0f;
    float x = (gx + 1.0f) * 0.5f * (float)(w - 1);
    float y = (gy + 1.0f) * 0.5f * (float)(h - 1);
    float x0f = floorf(x), y0f = floorf(y);
    int x0 = (int)x0f, y0 = (int)y0f;
    float wx1 = x - x0f, wy1 = y - y0f;
    float wx0 = 1.0f - wx1, wy0 = 1.0f - wy1;
    const float* plane = map + ((size_t)(b * C + cl)) * h * w;
    auto tap = [&](int xi, int yi) -> float {
        bool v = (xi >= 0) && (xi < w) && (yi >= 0) && (yi < h);
        int xc = min(max(xi, 0), w - 1);
        int yc = min(max(yi, 0), h - 1);
        return v ? plane[yc * w + xc] : 0.0f;
    };
    float v = tap(x0, y0) * (wx0 * wy0) + tap(x0 + 1, y0) * (wx1 * wy0) +
              tap(x0, y0 + 1) * (wx0 * wy1) + tap(x0 + 1, y0 + 1) * (wx1 * wy1);

    red[c] = v * v;
    __syncthreads();
    #pragma unroll
    for (int off = 128; off > 0; off >>= 1) {
        if (off < segsize && cl < off) red[c] += red[c + off];
        __syncthreads();
    }
    float norm = sqrtf(red[base]);
    float denom = fmaxf(norm, 1e-12f);
    X[(size_t)col * KTOT + c] = v / denom;
}

// ===== GEMM (bf16 MFMA): out[256,4096] = Mw[256,704] * X^T + bias =====
__global__ __launch_bounds__(256) void gemm_mfma(const float* __restrict__ Mw,
                                                 const float* __restrict__ X,
                                                 const float* __restrict__ biasf,
                                                 float* __restrict__ out) {
    __shared__ short As[64 * 68];
    __shared__ short Bs[64 * 68];
    int tid = threadIdx.x;
    int lane = tid & 63, w = tid >> 6;
    int r = lane & 15, quad = lane >> 4;
    int rowBase = blockIdx.y * 64, colBase = blockIdx.x * 64;
    int sm = tid >> 2, skq = (tid & 3) << 4;

    const float* pa = Mw + (size_t)(rowBase + sm) * KTOT + skq;
    const float* pb = X + (size_t)(colBase + sm) * KTOT + skq;
    float4 a0 = *(const float4*)(pa + 0), a1 = *(const float4*)(pa + 4);
    float4 a2 = *(const float4*)(pa + 8), a3 = *(const float4*)(pa + 12);
    float4 b0 = *(const float4*)(pb + 0), b1 = *(const float4*)(pb + 4);
    float4 b2 = *(const float4*)(pb + 8), b3 = *(const float4*)(pb + 12);

    f4v acc[4];
    #pragma unroll
    for (int t = 0; t < 4; ++t) acc[t] = (f4v)0.0f;

    for (int kt = 0; kt < 11; ++kt) {
        __syncthreads();
        {
            s4v v0 = { f2bf(a0.x), f2bf(a0.y), f2bf(a0.z), f2bf(a0.w) };
            s4v v1 = { f2bf(a1.x), f2bf(a1.y), f2bf(a1.z), f2bf(a1.w) };
            s4v v2 = { f2bf(a2.x), f2bf(a2.y), f2bf(a2.z), f2bf(a2.w) };
            s4v v3 = { f2bf(a3.x), f2bf(a3.y), f2bf(a3.z), f2bf(a3.w) };
            *(s4v*)&As[sm * 68 + skq + 0]  = v0;
            *(s4v*)&As[sm * 68 + skq + 4]  = v1;
            *(s4v*)&As[sm * 68 + skq + 8]  = v2;
            *(s4v*)&As[sm * 68 + skq + 12] = v3;
            s4v u0 = { f2bf(b0.x), f2bf(b0.y), f2bf(b0.z), f2bf(b0.w) };
            s4v u1 = { f2bf(b1.x), f2bf(b1.y), f2bf(b1.z), f2bf(b1.w) };
            s4v u2 = { f2bf(b2.x), f2bf(b2.y), f2bf(b2.z), f2bf(b2.w) };
            s4v u3 = { f2bf(b3.x), f2bf(b3.y), f2bf(b3.z), f2bf(b3.w) };
            *(s4v*)&Bs[sm * 68 + skq + 0]  = u0;
            *(s4v*)&Bs[sm * 68 + skq + 4]  = u1;
            *(s4v*)&Bs[sm * 68 + skq + 8]  = u2;
            *(s4v*)&Bs[sm * 68 + skq + 12] = u3;
        }
        __syncthreads();
        if (kt < 10) {
            pa += 64; pb += 64;
            a0 = *(const float4*)(pa + 0); a1 = *(const float4*)(pa + 4);
            a2 = *(const float4*)(pa + 8); a3 = *(const float4*)(pa + 12);
            b0 = *(const float4*)(pb + 0); b1 = *(const float4*)(pb + 4);
            b2 = *(const float4*)(pb + 8); b3 = *(const float4*)(pb + 12);
        }
        #pragma unroll
        for (int kk = 0; kk < 2; ++kk) {
            int aoff = (w * 16 + r) * 68 + kk * 32 + quad * 8;
            s4v alo = *(s4v*)&As[aoff];
            s4v ahi = *(s4v*)&As[aoff + 4];
            s8v af;
            af[0] = alo[0]; af[1] = alo[1]; af[2] = alo[2]; af[3] = alo[3];
            af[4] = ahi[0]; af[5] = ahi[1]; af[6] = ahi[2]; af[7] = ahi[3];
            #pragma unroll
            for (int t = 0; t < 4; ++t) {
                int boff = (t * 16 + r) * 68 + kk * 32 + quad * 8;
                s4v blo = *(s4v*)&Bs[boff];
                s4v bhi = *(s4v*)&Bs[boff + 4];
                s8v bf;
                bf[0] = blo[0]; bf[1] = blo[1]; bf[2] = blo[2]; bf[3] = blo[3];
                bf[4] = bhi[0]; bf[5] = bhi[1]; bf[6] = bhi[2]; bf[7] = bhi[3];
                acc[t] = __builtin_amdgcn_mfma_f32_16x16x32_bf16(af, bf, acc[t], 0, 0, 0);
            }
        }
    }
    #pragma unroll
    for (int t = 0; t < 4; ++t) {
        int colg = colBase + t * 16 + r;
        size_t obase = (size_t)(colg >> 10) * (256 * NKP) + (size_t)(colg & 1023);
        #pragma unroll
        for (int reg = 0; reg < 4; ++reg) {
            int row = rowBase + w * 16 + quad * 4 + reg;
            out[obase + (size_t)row * NKP] = acc[t][reg] + biasf[row];
        }
    }
}

// ================= launch =================
extern "C" void kernel_launch(void* const* d_in, const int* in_sizes, int n_in,
                              void* d_out, int out_size, void* d_ws, size_t ws_size,
                              hipStream_t stream) {
    const float* scores  = (const float*)d_in[0];
    const float* d1      = (const float*)d_in[1];
    const float* d2      = (const float*)d_in[2];
    const float* cDa     = (const float*)d_in[3];
    const float* d4      = (const float*)d_in[4];
    const float* lin0_w  = (const float*)d_in[5];
    const float* lin0_b  = (const float*)d_in[6];
    const float* lin1_w  = (const float*)d_in[7];
    const float* lin1_b  = (const float*)d_in[8];
    const float* lin2_w  = (const float*)d_in[9];
    const float* lin2_b  = (const float*)d_in[10];
    const float* merge_w = (const float*)d_in[11];
    const float* merge_b = (const float*)d_in[12];
    float* out = (float*)d_out;

    char* ws = (char*)d_ws;
    float* MASK = (float*)ws;                                          // BHW floats
    float* Xbuf = (float*)ws;                                          // aliases (used after NMS)
    unsigned long long* cand  = (unsigned long long*)(ws + 14745600);  // 524,288 B
    int* cnt                  = (int*)(ws + 15269888);                 // 1,024 B (padded)
    int* fidx                 = (int*)(ws + 15401984);                 // 16,384 B
    float* Mw                 = (float*)(ws + 15418368);               // 720,896 B
    float* biasf              = (float*)(ws + 16139264);               // 1,024 B
    int* perm                 = (int*)(ws + 16140288);                 // 16,384 B

    dim3 tgrid(W / 32, H / 32, B);   // (20,15,4)

    fuse_all<<<705, 256, 0, stream>>>(merge_w, merge_b, lin0_w, lin0_b, lin1_w, lin1_b,
                                      lin2_w, lin2_b, Mw, biasf, cnt);
    nms1<<<tgrid, 256, 0, stream>>>(scores, MASK);
    nms2_compact<<<tgrid, 256, 0, stream>>>(scores, MASK, cand, cnt);
    topk<<<B, 1024, 0, stream>>>(cand, cnt, out, fidx, perm);
    sample_all<<<B * NKP, KTOT, 0, stream>>>(d1, d2, cDa, d4, fidx, perm, Xbuf);
    gemm_mfma<<<dim3(NCOL / 64, 256 / 64), 256, 0, stream>>>(Mw, Xbuf, biasf, out + B * NKP * 3);
}